// Round 1
// baseline (619.817 us; speedup 1.0000x reference)
//
#include <hip/hip_runtime.h>
#include <math.h>

constexpr int B = 2, A = 900, ED = 256, NG = 8, NCAM = 6, NL = 4, NP = 7;
constexpr int NJ = NG * NCAM * NL * NP;   // 1344
constexpr int NBA = B * A;                // 1800
constexpr int NE = NCAM * NL * NP;        // 168 point-level entries

__constant__ float FIXS[NP][3] = {
  {0.f,0.f,0.f},{0.45f,0.f,0.f},{-0.45f,0.f,0.f},
  {0.f,0.45f,0.f},{0.f,-0.45f,0.f},{0.f,0.f,0.45f},{0.f,0.f,-0.45f}};

__constant__ int cH[NL]  = {64,32,16,8};
__constant__ int cW[NL]  = {176,88,44,22};
__constant__ int cHW[NL] = {11264,2816,704,176};
// float offsets of each level inside the channel-last transposed buffer
__constant__ long long cLOFF[NL] = {0LL, 34603008LL, 43253760LL, 45416448LL};

// ---------------- transpose [BC, C, HW] -> [BC, HW, C] ----------------
__global__ __launch_bounds__(256) void k_transpose(const float* __restrict__ in,
                                                   float* __restrict__ out, int HW)
{
  __shared__ float tile[32][33];
  const int bc  = blockIdx.z;
  const int ch0 = blockIdx.y * 32;
  const int s0  = blockIdx.x * 32;
  const int tx = threadIdx.x, ty = threadIdx.y;  // (32,8)
  const float* ip = in  + (size_t)bc * ED * HW;
  float*       op = out + (size_t)bc * HW * ED;
#pragma unroll
  for (int kk = 0; kk < 4; ++kk) {
    int s = s0 + tx;
    if (s < HW) tile[ty + kk*8][tx] = ip[(size_t)(ch0 + ty + kk*8) * HW + s];
  }
  __syncthreads();
#pragma unroll
  for (int kk = 0; kk < 4; ++kk) {
    int s = s0 + ty + kk*8;
    if (s < HW) op[(size_t)s * ED + ch0 + tx] = tile[tx][ty + kk*8];
  }
}

// ---------------- FC: wraw[1800,1344] = (inst+emb) @ w_fc^T + b_fc ----------------
__global__ __launch_bounds__(256) void k_fc(const float* __restrict__ inst,
    const float* __restrict__ emb, const float* __restrict__ w_fc,
    const float* __restrict__ b_fc, float* __restrict__ wraw)
{
  __shared__ float fsh[8][ED];
  const int a0 = blockIdx.x * 8;
  const int t = threadIdx.x;
#pragma unroll
  for (int k = 0; k < 8; ++k) {
    size_t idx = (size_t)(a0 + k) * ED + t;
    fsh[k][t] = inst[idx] + emb[idx];
  }
  __syncthreads();
  const int nj = (t < 64) ? 6 : 5;      // 1344 = 5*256 + 64 (wave-uniform split)
  float acc[6][8];
#pragma unroll
  for (int jj = 0; jj < 6; ++jj)
#pragma unroll
    for (int k = 0; k < 8; ++k) acc[jj][k] = 0.f;

  for (int ch = 0; ch < ED; ch += 4) {
    float4 fv[8];
#pragma unroll
    for (int k = 0; k < 8; ++k) fv[k] = *(const float4*)&fsh[k][ch];
    for (int jj = 0; jj < nj; ++jj) {
      const int j = t + jj*256;
      const float4 w4 = *(const float4*)&w_fc[(size_t)j*ED + ch];
#pragma unroll
      for (int k = 0; k < 8; ++k)
        acc[jj][k] += w4.x*fv[k].x + w4.y*fv[k].y + w4.z*fv[k].z + w4.w*fv[k].w;
    }
  }
  for (int jj = 0; jj < nj; ++jj) {
    const int j = t + jj*256;
    const float bj = b_fc[j];
#pragma unroll
    for (int k = 0; k < 8; ++k)
      wraw[(size_t)(a0+k)*NJ + j] = acc[jj][k] + bj;
  }
}

// ---------------- fused: softmax + projection + bilinear aggregation ----------------
template<bool TR>
__global__ __launch_bounds__(256) void k_sample(
    const float* __restrict__ anchor, const float* __restrict__ proj,
    const float* __restrict__ wh, const float* __restrict__ wraw,
    const float* __restrict__ tfeat,
    const float* __restrict__ f0, const float* __restrict__ f1,
    const float* __restrict__ f2, const float* __restrict__ f3,
    float* __restrict__ fused)
{
  __shared__ float wsh[NJ];
  __shared__ float gridsh[NCAM][NP][2];
  __shared__ int   exi[NE], eyi[NE], efl[NE];
  __shared__ float ewx[NE], ewy[NE];

  const int ba = blockIdx.x;
  const int b  = ba / A;
  const int t  = threadIdx.x;

  for (int j = t; j < NJ; j += 256) wsh[j] = wraw[(size_t)ba*NJ + j];

  if (t < NCAM*NP) {
    const int c = t / NP, p = t % NP;
    const float* an = anchor + (size_t)ba * 8;
    const float sx = expf(an[3]), sy = expf(an[4]), sz = expf(an[5]);
    const float sn = an[6], cs = an[7];
    const float kx = FIXS[p][0]*sx, ky = FIXS[p][1]*sy, kz = FIXS[p][2]*sz;
    const float px = cs*kx - sn*ky + an[0];
    const float py = sn*kx + cs*ky + an[1];
    const float pz = kz + an[2];
    const float* P = proj + ((size_t)(b*NCAM + c))*16;
    const float X = P[0]*px + P[1]*py + P[2]*pz  + P[3];
    const float Y = P[4]*px + P[5]*py + P[6]*pz  + P[7];
    const float Z = P[8]*px + P[9]*py + P[10]*pz + P[11];
    const float zc  = fmaxf(Z, 1e-5f);
    const float whx = fmaxf(wh[(b*NCAM+c)*2+0], 1e-5f);
    const float why = fmaxf(wh[(b*NCAM+c)*2+1], 1e-5f);
    gridsh[c][p][0] = (X/zc/whx)*2.f - 1.f;
    gridsh[c][p][1] = (Y/zc/why)*2.f - 1.f;
  }
  __syncthreads();

  if (t < NE) {
    const int c = t / (NL*NP); const int r = t % (NL*NP);
    const int l = r / NP, p = r % NP;
    const int Wl = cW[l], Hl = cH[l];
    const float gx = (gridsh[c][p][0] + 1.f) * (Wl * 0.5f) - 0.5f;
    const float gy = (gridsh[c][p][1] + 1.f) * (Hl * 0.5f) - 0.5f;
    const float x0f = floorf(gx), y0f = floorf(gy);
    const bool vx0 = (x0f >=  0.f) & (x0f <= (float)(Wl-1));
    const bool vx1 = (x0f >= -1.f) & (x0f <= (float)(Wl-2));
    const bool vy0 = (y0f >=  0.f) & (y0f <= (float)(Hl-1));
    const bool vy1 = (y0f >= -1.f) & (y0f <= (float)(Hl-2));
    efl[t] = ((vx0&&vy0)?1:0) | ((vx1&&vy0)?2:0) | ((vx0&&vy1)?4:0) | ((vx1&&vy1)?8:0);
    exi[t] = (int)fmaxf(fminf(x0f, 1e4f), -1e4f);
    eyi[t] = (int)fmaxf(fminf(y0f, 1e4f), -1e4f);
    ewx[t] = gx - x0f; ewy[t] = gy - y0f;
  }

  // group softmax over the 168 entries (8 groups x 32 lanes)
  {
    const int g = t >> 5, lane = t & 31;
    float m = -3.4e38f;
    for (int i = lane; i < NE; i += 32) m = fmaxf(m, wsh[i*NG + g]);
#pragma unroll
    for (int mk = 16; mk >= 1; mk >>= 1) m = fmaxf(m, __shfl_xor(m, mk));
    float s = 0.f;
    for (int i = lane; i < NE; i += 32) {
      const float e = expf(wsh[i*NG + g] - m);
      wsh[i*NG + g] = e;
      s += e;
    }
#pragma unroll
    for (int mk = 16; mk >= 1; mk >>= 1) s += __shfl_xor(s, mk);
    const float inv = 1.f / s;
    for (int i = lane; i < NE; i += 32) wsh[i*NG + g] *= inv;
  }
  __syncthreads();

  float acc = 0.f;
  const int g = t >> 5;
  const float* farr[4] = {f0, f1, f2, f3};
  for (int e = 0; e < NE; ++e) {
    const int fl = efl[e];
    if (fl == 0) continue;                       // block-uniform skip
    const int c = e / (NL*NP);
    const int l = (e / NP) % NL;
    const float aw  = wsh[e*NG + g];
    const int x0 = exi[e], y0 = eyi[e];
    const float wx1 = ewx[e], wy1 = ewy[e];
    const float wx0 = 1.f - wx1, wy0 = 1.f - wy1;
    float sv = 0.f;
    if (TR) {
      const int Wl = cW[l];
      const long long idx = (long long)((b*NCAM + c)*cHW[l] + y0*Wl + x0) * ED + t;
      const float* pb = tfeat + cLOFF[l] + idx;
      if (fl & 1) sv += wx0*wy0 * pb[0];
      if (fl & 2) sv += wx1*wy0 * pb[ED];
      if (fl & 4) sv += wx0*wy1 * pb[(long long)Wl*ED];
      if (fl & 8) sv += wx1*wy1 * pb[(long long)Wl*ED + ED];
    } else {
      const int Wl = cW[l];
      const float* pb = farr[l] + (long long)((b*NCAM + c)*ED + t) * cHW[l]
                                + (long long)(y0*Wl + x0);
      if (fl & 1) sv += wx0*wy0 * pb[0];
      if (fl & 2) sv += wx1*wy0 * pb[1];
      if (fl & 4) sv += wx0*wy1 * pb[Wl];
      if (fl & 8) sv += wx1*wy1 * pb[Wl+1];
    }
    acc += aw * sv;
  }
  fused[(size_t)ba*ED + t] = acc;
}

// ---------------- out = fused @ w_out^T + b_out ----------------
__global__ __launch_bounds__(256) void k_out(const float* __restrict__ fused,
    const float* __restrict__ w_out, const float* __restrict__ b_out,
    float* __restrict__ out)
{
  __shared__ float fsh[8][ED];
  const int a0 = blockIdx.x * 8;
  const int t = threadIdx.x;
#pragma unroll
  for (int k = 0; k < 8; ++k) fsh[k][t] = fused[(size_t)(a0+k)*ED + t];
  __syncthreads();
  float acc[8] = {0.f,0.f,0.f,0.f,0.f,0.f,0.f,0.f};
  for (int i = 0; i < ED; i += 4) {
    const float4 w4 = *(const float4*)&w_out[(size_t)t*ED + i];
#pragma unroll
    for (int k = 0; k < 8; ++k) {
      const float4 fv = *(const float4*)&fsh[k][i];
      acc[k] += w4.x*fv.x + w4.y*fv.y + w4.z*fv.z + w4.w*fv.w;
    }
  }
  const float bo = b_out[t];
#pragma unroll
  for (int k = 0; k < 8; ++k) out[(size_t)(a0+k)*ED + t] = acc[k] + bo;
}

extern "C" void kernel_launch(void* const* d_in, const int* in_sizes, int n_in,
                              void* d_out, int out_size, void* d_ws, size_t ws_size,
                              hipStream_t stream) {
  const float* inst   = (const float*)d_in[0];
  const float* anchor = (const float*)d_in[1];
  const float* emb    = (const float*)d_in[2];
  const float* feats[4] = {(const float*)d_in[3], (const float*)d_in[4],
                           (const float*)d_in[5], (const float*)d_in[6]};
  const float* proj  = (const float*)d_in[7];
  const float* wh    = (const float*)d_in[8];
  const float* w_fc  = (const float*)d_in[9];
  const float* b_fc  = (const float*)d_in[10];
  const float* w_out = (const float*)d_in[11];
  const float* b_out = (const float*)d_in[12];
  float* out = (float*)d_out;
  float* ws  = (float*)d_ws;

  const size_t TFEAT = 45957120ULL;                // floats, all 4 levels channel-last
  const size_t WRAW  = (size_t)NBA * NJ;           // 2,419,200
  const size_t FUSED = (size_t)NBA * ED;           // 460,800
  const bool tr = ws_size >= (TFEAT + WRAW + FUSED) * sizeof(float);

  float* tfeat = ws;
  float* wraw  = tr ? (ws + TFEAT) : ws;
  float* fusedp = wraw + WRAW;

  if (tr) {
    const int HWs[4] = {11264, 2816, 704, 176};
    const long long loffh[4] = {0LL, 34603008LL, 43253760LL, 45416448LL};
    for (int l = 0; l < 4; ++l) {
      dim3 g((HWs[l] + 31) / 32, ED / 32, B * NCAM);
      k_transpose<<<g, dim3(32, 8), 0, stream>>>(feats[l], tfeat + loffh[l], HWs[l]);
    }
  }

  k_fc<<<NBA / 8, 256, 0, stream>>>(inst, emb, w_fc, b_fc, wraw);

  if (tr)
    k_sample<true><<<NBA, 256, 0, stream>>>(anchor, proj, wh, wraw, tfeat,
        feats[0], feats[1], feats[2], feats[3], fusedp);
  else
    k_sample<false><<<NBA, 256, 0, stream>>>(anchor, proj, wh, wraw, tfeat,
        feats[0], feats[1], feats[2], feats[3], fusedp);

  k_out<<<NBA / 8, 256, 0, stream>>>(fusedp, w_out, b_out, out);
}

// Round 2
// 442.348 us; speedup vs baseline: 1.4012x; 1.4012x over previous
//
#include <hip/hip_runtime.h>
#include <math.h>

constexpr int B = 2, A = 900, ED = 256, NG = 8, NCAM = 6, NL = 4, NP = 7;
constexpr int NJ = NG * NCAM * NL * NP;   // 1344
constexpr int NBA = B * A;                // 1800
constexpr int NE = NCAM * NL * NP;        // 168 point-level entries

__constant__ float FIXS[NP][3] = {
  {0.f,0.f,0.f},{0.45f,0.f,0.f},{-0.45f,0.f,0.f},
  {0.f,0.45f,0.f},{0.f,-0.45f,0.f},{0.f,0.f,0.45f},{0.f,0.f,-0.45f}};

__constant__ int cH[NL]  = {64,32,16,8};
__constant__ int cW[NL]  = {176,88,44,22};
__constant__ int cHW[NL] = {11264,2816,704,176};
// float offsets of each level inside the channel-last transposed buffer
__constant__ long long cLOFF[NL] = {0LL, 34603008LL, 43253760LL, 45416448LL};

// ---------------- generic 2D transpose: in[R,C] -> out[C,R], batched on z ----
__global__ __launch_bounds__(256) void k_tr(const float* __restrict__ in,
                                            float* __restrict__ out, int R, int C)
{
  __shared__ float tile[32][33];
  const size_t base = (size_t)blockIdx.z * R * C;
  const int r0 = blockIdx.y * 32, c0 = blockIdx.x * 32;
  const int tx = threadIdx.x, ty = threadIdx.y;  // (32,8)
#pragma unroll
  for (int kk = 0; kk < 4; ++kk) {
    const int r = r0 + ty + kk*8, c = c0 + tx;
    if (r < R && c < C) tile[ty + kk*8][tx] = in[base + (size_t)r*C + c];
  }
  __syncthreads();
#pragma unroll
  for (int kk = 0; kk < 4; ++kk) {
    const int c = c0 + ty + kk*8, r = r0 + tx;
    if (r < R && c < C) out[base + (size_t)c*R + r] = tile[tx][ty + kk*8];
  }
}

// ------- FC: wraw[1800,1344] = (inst+emb) @ wt + b_fc, wt = w_fc^T [256,1344] -------
// grid (225, 7), block 192: a-tile 8, j-tile 192. Lane t <-> column j (coalesced).
__global__ __launch_bounds__(192) void k_fc(const float* __restrict__ inst,
    const float* __restrict__ emb, const float* __restrict__ wt,
    const float* __restrict__ b_fc, float* __restrict__ wraw)
{
  __shared__ float fsh[8][ED];
  const int a0 = blockIdx.x * 8;
  const int j  = blockIdx.y * 192 + threadIdx.x;
  const int t  = threadIdx.x;

  for (int i = t; i < 8 * ED; i += 192) {
    const int a = i >> 8, k = i & 255;
    const size_t idx = (size_t)(a0 + a) * ED + k;
    fsh[a][k] = inst[idx] + emb[idx];
  }
  __syncthreads();

  float acc[8] = {0.f,0.f,0.f,0.f,0.f,0.f,0.f,0.f};
  for (int k = 0; k < ED; k += 4) {
    float w0 = wt[(size_t)(k+0)*NJ + j];
    float w1 = wt[(size_t)(k+1)*NJ + j];
    float w2 = wt[(size_t)(k+2)*NJ + j];
    float w3 = wt[(size_t)(k+3)*NJ + j];
#pragma unroll
    for (int a = 0; a < 8; ++a)
      acc[a] += w0*fsh[a][k] + w1*fsh[a][k+1] + w2*fsh[a][k+2] + w3*fsh[a][k+3];
  }
  const float bj = b_fc[j];
#pragma unroll
  for (int a = 0; a < 8; ++a)
    wraw[(size_t)(a0+a)*NJ + j] = acc[a] + bj;
}

// ---------------- fused: softmax + projection + bilinear aggregation ----------------
template<bool TR>
__global__ __launch_bounds__(256) void k_sample(
    const float* __restrict__ anchor, const float* __restrict__ proj,
    const float* __restrict__ wh, const float* __restrict__ wraw,
    const float* __restrict__ tfeat,
    const float* __restrict__ f0, const float* __restrict__ f1,
    const float* __restrict__ f2, const float* __restrict__ f3,
    float* __restrict__ fused)
{
  __shared__ float wsh[NJ];
  __shared__ float gridsh[NCAM][NP][2];
  __shared__ int   exi[NE], eyi[NE], efl[NE];
  __shared__ float ewx[NE], ewy[NE];

  const int ba = blockIdx.x;
  const int b  = ba / A;
  const int t  = threadIdx.x;

  for (int j = t; j < NJ; j += 256) wsh[j] = wraw[(size_t)ba*NJ + j];

  if (t < NCAM*NP) {
    const int c = t / NP, p = t % NP;
    const float* an = anchor + (size_t)ba * 8;
    const float sx = expf(an[3]), sy = expf(an[4]), sz = expf(an[5]);
    const float sn = an[6], cs = an[7];
    const float kx = FIXS[p][0]*sx, ky = FIXS[p][1]*sy, kz = FIXS[p][2]*sz;
    const float px = cs*kx - sn*ky + an[0];
    const float py = sn*kx + cs*ky + an[1];
    const float pz = kz + an[2];
    const float* P = proj + ((size_t)(b*NCAM + c))*16;
    const float X = P[0]*px + P[1]*py + P[2]*pz  + P[3];
    const float Y = P[4]*px + P[5]*py + P[6]*pz  + P[7];
    const float Z = P[8]*px + P[9]*py + P[10]*pz + P[11];
    const float zc  = fmaxf(Z, 1e-5f);
    const float whx = fmaxf(wh[(b*NCAM+c)*2+0], 1e-5f);
    const float why = fmaxf(wh[(b*NCAM+c)*2+1], 1e-5f);
    gridsh[c][p][0] = (X/zc/whx)*2.f - 1.f;
    gridsh[c][p][1] = (Y/zc/why)*2.f - 1.f;
  }
  __syncthreads();

  if (t < NE) {
    const int c = t / (NL*NP); const int r = t % (NL*NP);
    const int l = r / NP, p = r % NP;
    const int Wl = cW[l], Hl = cH[l];
    const float gx = (gridsh[c][p][0] + 1.f) * (Wl * 0.5f) - 0.5f;
    const float gy = (gridsh[c][p][1] + 1.f) * (Hl * 0.5f) - 0.5f;
    const float x0f = floorf(gx), y0f = floorf(gy);
    const bool vx0 = (x0f >=  0.f) & (x0f <= (float)(Wl-1));
    const bool vx1 = (x0f >= -1.f) & (x0f <= (float)(Wl-2));
    const bool vy0 = (y0f >=  0.f) & (y0f <= (float)(Hl-1));
    const bool vy1 = (y0f >= -1.f) & (y0f <= (float)(Hl-2));
    efl[t] = ((vx0&&vy0)?1:0) | ((vx1&&vy0)?2:0) | ((vx0&&vy1)?4:0) | ((vx1&&vy1)?8:0);
    exi[t] = (int)fmaxf(fminf(x0f, 1e4f), -1e4f);
    eyi[t] = (int)fmaxf(fminf(y0f, 1e4f), -1e4f);
    ewx[t] = gx - x0f; ewy[t] = gy - y0f;
  }

  // group softmax over the 168 entries (8 groups x 32 lanes)
  {
    const int g = t >> 5, lane = t & 31;
    float m = -3.4e38f;
    for (int i = lane; i < NE; i += 32) m = fmaxf(m, wsh[i*NG + g]);
#pragma unroll
    for (int mk = 16; mk >= 1; mk >>= 1) m = fmaxf(m, __shfl_xor(m, mk));
    float s = 0.f;
    for (int i = lane; i < NE; i += 32) {
      const float e = expf(wsh[i*NG + g] - m);
      wsh[i*NG + g] = e;
      s += e;
    }
#pragma unroll
    for (int mk = 16; mk >= 1; mk >>= 1) s += __shfl_xor(s, mk);
    const float inv = 1.f / s;
    for (int i = lane; i < NE; i += 32) wsh[i*NG + g] *= inv;
  }
  __syncthreads();

  float acc = 0.f;
  const int g = t >> 5;
  const float* farr[4] = {f0, f1, f2, f3};
  for (int e = 0; e < NE; ++e) {
    const int fl = efl[e];
    if (fl == 0) continue;                       // block-uniform skip
    const int c = e / (NL*NP);
    const int l = (e / NP) % NL;
    const float aw  = wsh[e*NG + g];
    const int x0 = exi[e], y0 = eyi[e];
    const float wx1 = ewx[e], wy1 = ewy[e];
    const float wx0 = 1.f - wx1, wy0 = 1.f - wy1;
    float sv = 0.f;
    if (TR) {
      const int Wl = cW[l];
      const long long idx = (long long)((b*NCAM + c)*cHW[l] + y0*Wl + x0) * ED + t;
      const float* pb = tfeat + cLOFF[l] + idx;
      if (fl & 1) sv += wx0*wy0 * pb[0];
      if (fl & 2) sv += wx1*wy0 * pb[ED];
      if (fl & 4) sv += wx0*wy1 * pb[(long long)Wl*ED];
      if (fl & 8) sv += wx1*wy1 * pb[(long long)Wl*ED + ED];
    } else {
      const int Wl = cW[l];
      const float* pb = farr[l] + (long long)((b*NCAM + c)*ED + t) * cHW[l]
                                + (long long)(y0*Wl + x0);
      if (fl & 1) sv += wx0*wy0 * pb[0];
      if (fl & 2) sv += wx1*wy0 * pb[1];
      if (fl & 4) sv += wx0*wy1 * pb[Wl];
      if (fl & 8) sv += wx1*wy1 * pb[Wl+1];
    }
    acc += aw * sv;
  }
  fused[(size_t)ba*ED + t] = acc;
}

// ---------------- out = fused @ w_out^T + b_out ----------------
__global__ __launch_bounds__(256) void k_out(const float* __restrict__ fused,
    const float* __restrict__ w_out, const float* __restrict__ b_out,
    float* __restrict__ out)
{
  __shared__ float fsh[8][ED];
  const int a0 = blockIdx.x * 8;
  const int t = threadIdx.x;
#pragma unroll
  for (int k = 0; k < 8; ++k) fsh[k][t] = fused[(size_t)(a0+k)*ED + t];
  __syncthreads();
  float acc[8] = {0.f,0.f,0.f,0.f,0.f,0.f,0.f,0.f};
  for (int i = 0; i < ED; i += 4) {
    const float4 w4 = *(const float4*)&w_out[(size_t)t*ED + i];
#pragma unroll
    for (int k = 0; k < 8; ++k) {
      const float4 fv = *(const float4*)&fsh[k][i];
      acc[k] += w4.x*fv.x + w4.y*fv.y + w4.z*fv.z + w4.w*fv.w;
    }
  }
  const float bo = b_out[t];
#pragma unroll
  for (int k = 0; k < 8; ++k) out[(size_t)(a0+k)*ED + t] = acc[k] + bo;
}

extern "C" void kernel_launch(void* const* d_in, const int* in_sizes, int n_in,
                              void* d_out, int out_size, void* d_ws, size_t ws_size,
                              hipStream_t stream) {
  const float* inst   = (const float*)d_in[0];
  const float* anchor = (const float*)d_in[1];
  const float* emb    = (const float*)d_in[2];
  const float* feats[4] = {(const float*)d_in[3], (const float*)d_in[4],
                           (const float*)d_in[5], (const float*)d_in[6]};
  const float* proj  = (const float*)d_in[7];
  const float* wh    = (const float*)d_in[8];
  const float* w_fc  = (const float*)d_in[9];
  const float* b_fc  = (const float*)d_in[10];
  const float* w_out = (const float*)d_in[11];
  const float* b_out = (const float*)d_in[12];
  float* out = (float*)d_out;
  float* ws  = (float*)d_ws;

  const size_t TFEAT = 45957120ULL;                // floats, all 4 levels channel-last
  const size_t WRAW  = (size_t)NBA * NJ;           // 2,419,200
  const size_t FUSED = (size_t)NBA * ED;           // 460,800
  const size_t WT    = (size_t)ED * NJ;            // 344,064
  const bool tr = ws_size >= (TFEAT + WRAW + FUSED + WT) * sizeof(float);

  float* tfeat  = ws;
  float* wraw   = tr ? (ws + TFEAT) : ws;
  float* fusedp = wraw + WRAW;
  float* wt     = fusedp + FUSED;

  // w_fc [1344,256] -> wt [256,1344]
  k_tr<<<dim3(ED/32, NJ/32, 1), dim3(32,8), 0, stream>>>(w_fc, wt, NJ, ED);

  if (tr) {
    const int HWs[4] = {11264, 2816, 704, 176};
    const long long loffh[4] = {0LL, 34603008LL, 43253760LL, 45416448LL};
    for (int l = 0; l < 4; ++l) {
      dim3 g((HWs[l] + 31) / 32, ED / 32, B * NCAM);
      k_tr<<<g, dim3(32, 8), 0, stream>>>(feats[l], tfeat + loffh[l], ED, HWs[l]);
    }
  }

  k_fc<<<dim3(NBA / 8, 7), 192, 0, stream>>>(inst, emb, wt, b_fc, wraw);

  if (tr)
    k_sample<true><<<NBA, 256, 0, stream>>>(anchor, proj, wh, wraw, tfeat,
        feats[0], feats[1], feats[2], feats[3], fusedp);
  else
    k_sample<false><<<NBA, 256, 0, stream>>>(anchor, proj, wh, wraw, tfeat,
        feats[0], feats[1], feats[2], feats[3], fusedp);

  k_out<<<NBA / 8, 256, 0, stream>>>(fusedp, w_out, b_out, out);
}

// Round 3
// 414.460 us; speedup vs baseline: 1.4955x; 1.0673x over previous
//
#include <hip/hip_runtime.h>
#include <math.h>

constexpr int B = 2, A = 900, ED = 256, NG = 8, NCAM = 6, NL = 4, NP = 7;
constexpr int NJ = NG * NCAM * NL * NP;   // 1344
constexpr int NBA = B * A;                // 1800
constexpr int NE = NCAM * NL * NP;        // 168 point-level entries

__constant__ float FIXS[NP][3] = {
  {0.f,0.f,0.f},{0.45f,0.f,0.f},{-0.45f,0.f,0.f},
  {0.f,0.45f,0.f},{0.f,-0.45f,0.f},{0.f,0.f,0.45f},{0.f,0.f,-0.45f}};

__constant__ int cH[NL]  = {64,32,16,8};
__constant__ int cW[NL]  = {176,88,44,22};
__constant__ int cHW[NL] = {11264,2816,704,176};

// ---------------- generic 2D transpose: in[R,C] -> out[C,R] (used for w_fc only) ----
__global__ __launch_bounds__(256) void k_tr(const float* __restrict__ in,
                                            float* __restrict__ out, int R, int C)
{
  __shared__ float tile[32][33];
  const int r0 = blockIdx.y * 32, c0 = blockIdx.x * 32;
  const int tx = threadIdx.x, ty = threadIdx.y;  // (32,8)
#pragma unroll
  for (int kk = 0; kk < 4; ++kk) {
    const int r = r0 + ty + kk*8, c = c0 + tx;
    if (r < R && c < C) tile[ty + kk*8][tx] = in[(size_t)r*C + c];
  }
  __syncthreads();
#pragma unroll
  for (int kk = 0; kk < 4; ++kk) {
    const int c = c0 + ty + kk*8, r = r0 + tx;
    if (r < R && c < C) out[(size_t)c*R + r] = tile[tx][ty + kk*8];
  }
}

// ------- FC: wraw[1800,1344] = (inst+emb) @ wt + b_fc, wt = w_fc^T [256,1344] -------
__global__ __launch_bounds__(192) void k_fc(const float* __restrict__ inst,
    const float* __restrict__ emb, const float* __restrict__ wt,
    const float* __restrict__ b_fc, float* __restrict__ wraw)
{
  __shared__ float fsh[8][ED];
  const int a0 = blockIdx.x * 8;
  const int j  = blockIdx.y * 192 + threadIdx.x;
  const int t  = threadIdx.x;

  for (int i = t; i < 8 * ED; i += 192) {
    const int a = i >> 8, k = i & 255;
    const size_t idx = (size_t)(a0 + a) * ED + k;
    fsh[a][k] = inst[idx] + emb[idx];
  }
  __syncthreads();

  float acc[8] = {0.f,0.f,0.f,0.f,0.f,0.f,0.f,0.f};
  for (int k = 0; k < ED; k += 4) {
    float w0 = wt[(size_t)(k+0)*NJ + j];
    float w1 = wt[(size_t)(k+1)*NJ + j];
    float w2 = wt[(size_t)(k+2)*NJ + j];
    float w3 = wt[(size_t)(k+3)*NJ + j];
#pragma unroll
    for (int a = 0; a < 8; ++a)
      acc[a] += w0*fsh[a][k] + w1*fsh[a][k+1] + w2*fsh[a][k+2] + w3*fsh[a][k+3];
  }
  const float bj = b_fc[j];
#pragma unroll
  for (int a = 0; a < 8; ++a)
    wraw[(size_t)(a0+a)*NJ + j] = acc[a] + bj;
}

// ------- fused: softmax + projection + compacted bilinear gather (native layout) ----
__global__ __launch_bounds__(256) void k_sample_g(
    const float* __restrict__ anchor, const float* __restrict__ proj,
    const float* __restrict__ wh, const float* __restrict__ wraw,
    const float* __restrict__ f0, const float* __restrict__ f1,
    const float* __restrict__ f2, const float* __restrict__ f3,
    float* __restrict__ fused)
{
  __shared__ float wsh[NJ];
  __shared__ float gridsh[NCAM][NP][2];
  __shared__ const float* cbase[NE];   // per valid entry: base ptr (bc,l,y0,x0), ch 0
  __shared__ float4 cwt[NE];           // bilinear weights w00,w10,w01,w11
  __shared__ int4   cmeta[NE];         // W, HW, flags, orig entry idx
  __shared__ int wcnt[4];

  const int ba = blockIdx.x;
  const int b  = ba / A;
  const int t  = threadIdx.x;

  for (int j = t; j < NJ; j += 256) wsh[j] = wraw[(size_t)ba*NJ + j];

  if (t < NCAM*NP) {
    const int c = t / NP, p = t % NP;
    const float* an = anchor + (size_t)ba * 8;
    const float sx = expf(an[3]), sy = expf(an[4]), sz = expf(an[5]);
    const float sn = an[6], cs = an[7];
    const float kx = FIXS[p][0]*sx, ky = FIXS[p][1]*sy, kz = FIXS[p][2]*sz;
    const float px = cs*kx - sn*ky + an[0];
    const float py = sn*kx + cs*ky + an[1];
    const float pz = kz + an[2];
    const float* P = proj + ((size_t)(b*NCAM + c))*16;
    const float X = P[0]*px + P[1]*py + P[2]*pz  + P[3];
    const float Y = P[4]*px + P[5]*py + P[6]*pz  + P[7];
    const float Z = P[8]*px + P[9]*py + P[10]*pz + P[11];
    const float zc  = fmaxf(Z, 1e-5f);
    const float whx = fmaxf(wh[(b*NCAM+c)*2+0], 1e-5f);
    const float why = fmaxf(wh[(b*NCAM+c)*2+1], 1e-5f);
    gridsh[c][p][0] = (X/zc/whx)*2.f - 1.f;
    gridsh[c][p][1] = (Y/zc/why)*2.f - 1.f;
  }
  __syncthreads();

  // per-entry tap computation in registers, then deterministic compaction
  bool valid = false;
  int fl = 0, Wl = 0, HWl = 0;
  float wx1 = 0.f, wy1 = 0.f;
  const float* bptr = nullptr;
  if (t < NE) {
    const int c = t / (NL*NP); const int r = t % (NL*NP);
    const int l = r / NP, p = r % NP;
    Wl = cW[l]; HWl = cHW[l];
    const int Hl = cH[l];
    const float gx = (gridsh[c][p][0] + 1.f) * (Wl * 0.5f) - 0.5f;
    const float gy = (gridsh[c][p][1] + 1.f) * (Hl * 0.5f) - 0.5f;
    const float x0f = floorf(gx), y0f = floorf(gy);
    const bool vx0 = (x0f >=  0.f) & (x0f <= (float)(Wl-1));
    const bool vx1 = (x0f >= -1.f) & (x0f <= (float)(Wl-2));
    const bool vy0 = (y0f >=  0.f) & (y0f <= (float)(Hl-1));
    const bool vy1 = (y0f >= -1.f) & (y0f <= (float)(Hl-2));
    fl = ((vx0&&vy0)?1:0) | ((vx1&&vy0)?2:0) | ((vx0&&vy1)?4:0) | ((vx1&&vy1)?8:0);
    if (fl) {
      wx1 = gx - x0f; wy1 = gy - y0f;
      const int x0 = (int)x0f, y0 = (int)y0f;     // in [-1, W-1] when fl != 0
      const float* fp = (l==0) ? f0 : (l==1) ? f1 : (l==2) ? f2 : f3;
      bptr = fp + (size_t)(b*NCAM + c) * ED * HWl + (long long)(y0*Wl + x0);
      valid = true;
    }
  }

  const unsigned long long mask = __ballot(valid);
  const int lane = t & 63, wv = t >> 6;
  if (lane == 0) wcnt[wv] = __popcll(mask);
  __syncthreads();
  int off = 0, nv = 0;
#pragma unroll
  for (int i = 0; i < 4; ++i) { if (i < wv) off += wcnt[i]; nv += wcnt[i]; }
  if (valid) {
    const int pos = off + __popcll(mask & ((1ull << lane) - 1ull));
    cbase[pos] = bptr;
    cwt[pos]   = make_float4((1.f-wx1)*(1.f-wy1), wx1*(1.f-wy1),
                             (1.f-wx1)*wy1,       wx1*wy1);
    cmeta[pos] = make_int4(Wl, HWl, fl, t);
  }

  // group softmax over the 168 entries (8 groups x 32 lanes)
  {
    const int g = t >> 5, ln = t & 31;
    float m = -3.4e38f;
    for (int i = ln; i < NE; i += 32) m = fmaxf(m, wsh[i*NG + g]);
#pragma unroll
    for (int mk = 16; mk >= 1; mk >>= 1) m = fmaxf(m, __shfl_xor(m, mk));
    float s = 0.f;
    for (int i = ln; i < NE; i += 32) {
      const float e = expf(wsh[i*NG + g] - m);
      wsh[i*NG + g] = e;
      s += e;
    }
#pragma unroll
    for (int mk = 16; mk >= 1; mk >>= 1) s += __shfl_xor(s, mk);
    const float inv = 1.f / s;
    for (int i = ln; i < NE; i += 32) wsh[i*NG + g] *= inv;
  }
  __syncthreads();

  float acc = 0.f;
  const int g = t >> 5;
  for (int i = 0; i < nv; ++i) {
    const float* bp = cbase[i];
    const float4 w4 = cwt[i];
    const int4 m = cmeta[i];
    const float* pb = bp + (long long)t * m.y;
    const float aw = wsh[m.w*NG + g];
    float sv = 0.f;
    const int f = m.z;
    if (f == 15) {
      sv = w4.x*pb[0] + w4.y*pb[1] + w4.z*pb[m.x] + w4.w*pb[m.x+1];
    } else {
      if (f & 1) sv += w4.x*pb[0];
      if (f & 2) sv += w4.y*pb[1];
      if (f & 4) sv += w4.z*pb[m.x];
      if (f & 8) sv += w4.w*pb[m.x+1];
    }
    acc += aw * sv;
  }
  fused[(size_t)ba*ED + t] = acc;
}

// ---------------- out = fused @ w_out^T + b_out ----------------
__global__ __launch_bounds__(256) void k_out(const float* __restrict__ fused,
    const float* __restrict__ w_out, const float* __restrict__ b_out,
    float* __restrict__ out)
{
  __shared__ float fsh[8][ED];
  const int a0 = blockIdx.x * 8;
  const int t = threadIdx.x;
#pragma unroll
  for (int k = 0; k < 8; ++k) fsh[k][t] = fused[(size_t)(a0+k)*ED + t];
  __syncthreads();
  float acc[8] = {0.f,0.f,0.f,0.f,0.f,0.f,0.f,0.f};
  for (int i = 0; i < ED; i += 4) {
    const float4 w4 = *(const float4*)&w_out[(size_t)t*ED + i];
#pragma unroll
    for (int k = 0; k < 8; ++k) {
      const float4 fv = *(const float4*)&fsh[k][i];
      acc[k] += w4.x*fv.x + w4.y*fv.y + w4.z*fv.z + w4.w*fv.w;
    }
  }
  const float bo = b_out[t];
#pragma unroll
  for (int k = 0; k < 8; ++k) out[(size_t)(a0+k)*ED + t] = acc[k] + bo;
}

extern "C" void kernel_launch(void* const* d_in, const int* in_sizes, int n_in,
                              void* d_out, int out_size, void* d_ws, size_t ws_size,
                              hipStream_t stream) {
  const float* inst   = (const float*)d_in[0];
  const float* anchor = (const float*)d_in[1];
  const float* emb    = (const float*)d_in[2];
  const float* f0 = (const float*)d_in[3];
  const float* f1 = (const float*)d_in[4];
  const float* f2 = (const float*)d_in[5];
  const float* f3 = (const float*)d_in[6];
  const float* proj  = (const float*)d_in[7];
  const float* wh    = (const float*)d_in[8];
  const float* w_fc  = (const float*)d_in[9];
  const float* b_fc  = (const float*)d_in[10];
  const float* w_out = (const float*)d_in[11];
  const float* b_out = (const float*)d_in[12];
  float* out = (float*)d_out;
  float* ws  = (float*)d_ws;

  const size_t WRAW  = (size_t)NBA * NJ;           // 2,419,200 floats
  const size_t FUSED = (size_t)NBA * ED;           // 460,800
  // workspace: wraw | fused | wt  (~13 MB total)
  float* wraw   = ws;
  float* fusedp = wraw + WRAW;
  float* wt     = fusedp + FUSED;

  // w_fc [1344,256] -> wt [256,1344]
  k_tr<<<dim3(ED/32, NJ/32, 1), dim3(32,8), 0, stream>>>(w_fc, wt, NJ, ED);

  k_fc<<<dim3(NBA / 8, 7), 192, 0, stream>>>(inst, emb, wt, b_fc, wraw);

  k_sample_g<<<NBA, 256, 0, stream>>>(anchor, proj, wh, wraw,
                                      f0, f1, f2, f3, fusedp);

  k_out<<<NBA / 8, 256, 0, stream>>>(fusedp, w_out, b_out, out);
}